// Round 7
// baseline (59.390 us; speedup 1.0000x reference)
//
#include <hip/hip_runtime.h>
#include <hip/hip_bf16.h>

#define HIDDEN 64
#define BATCH 2048
#define SFULL 1024
#define SM1 1023
#define LN_CLAMP -23.025850929940457f  // ln(1e-10)
#define PAIRS 8                        // 16 sp per block (grid.y = 64)

typedef __bf16 bf16x8 __attribute__((ext_vector_type(8)));
typedef float  f32x4  __attribute__((ext_vector_type(4)));

// Fragment cache layout in workspace: 19 units of [64 lanes][16B].
//  u 0..3  : a1[mt]      (bf16x8)
//  u 4..11 : a2[mt][c]   (u = 4 + mt*2 + c)
//  u 12,13 : a3[c]
//  u 14..17: c2init[mt]  (f32x4)
//  u 18    : c3init      (f32x4)
#define FRAG_UNITS 19
#define FRAG_BYTES (FRAG_UNITS * 64 * 16)

// Row permutation mapping MFMA D-layout rows to MFMA B-layout k-indices.
// For rho = 16*mt + 4*gg + r:  perm(rho) = 32*(mt>>1) + 8*gg + 4*(mt&1) + r.
// Hardware-verified in R2-R5 (absmax 0.0).
__device__ __forceinline__ int permrow(int rho) {
    return 32 * ((rho >> 4) >> 1) + 8 * ((rho >> 2) & 3) + 4 * ((rho >> 4) & 1) + (rho & 3);
}

// ---- packed bf16 helpers: 2 f32 -> 1 dword via v_cvt_pk_bf16_f32 ----------
__device__ __forceinline__ unsigned pk2(float lo, float hi) {
    union { __hip_bfloat162 h; unsigned u; } cv;
    float2 p; p.x = lo; p.y = hi;
    cv.h = __float22bfloat162_rn(p);
    return cv.u;
}

// relu + pack the 8 accumulator values (two f32x4 D-frags) into one B-frag.
// Mapping (R2-verified): frag[j] = relu(acc[base + (j>>2)][j&3]).
__device__ __forceinline__ bf16x8 relu_pack(const f32x4 a, const f32x4 b) {
    union { unsigned u[4]; bf16x8 v; } r;
    r.u[0] = pk2(fmaxf(a[0], 0.f), fmaxf(a[1], 0.f));
    r.u[1] = pk2(fmaxf(a[2], 0.f), fmaxf(a[3], 0.f));
    r.u[2] = pk2(fmaxf(b[0], 0.f), fmaxf(b[1], 0.f));
    r.u[3] = pk2(fmaxf(b[2], 0.f), fmaxf(b[3], 0.f));
    return r.v;
}

// feature B-frag {xt, t, x0, 1, xt, t, x0, 1} (A1 cols k>=4 are zero)
__device__ __forceinline__ bf16x8 feat_pack(float xt, float t, float x0) {
    union { unsigned u[4]; bf16x8 v; } r;
    r.u[0] = pk2(xt, t);
    r.u[1] = pk2(x0, 1.0f);
    r.u[2] = r.u[0]; r.u[3] = r.u[1];
    return r.v;
}

// ---------------- Kernel 0: one-time fragment gather (1 block) -------------
__global__ __launch_bounds__(256) void frag_setup_kernel(
    const float* __restrict__ W1, const float* __restrict__ b1,
    const float* __restrict__ W2, const float* __restrict__ b2,
    const float* __restrict__ Wout, const float* __restrict__ bout,
    char* __restrict__ F)
{
    const int lane = threadIdx.x & 63;
    const int wv   = threadIdx.x >> 6;
    const int col  = lane & 15;
    const int g    = lane >> 4;

    if (wv == 0) {
        // a1 (bias folded into k=3) + a3 + c3init
#pragma unroll
        for (int mt = 0; mt < 4; ++mt) {
            const int p2 = permrow(16 * mt + col);
            bf16x8 v;
#pragma unroll
            for (int j = 0; j < 8; ++j) {
                const int k = 8 * g + j;
                v[j] = (k < 3) ? (__bf16)W1[k * 64 + p2]
                     : (k == 3) ? (__bf16)b1[p2] : (__bf16)0.0f;
            }
            *(bf16x8*)(F + ((mt * 64 + lane) << 4)) = v;
        }
#pragma unroll
        for (int c = 0; c < 2; ++c) {
            bf16x8 v;
#pragma unroll
            for (int j = 0; j < 8; ++j)
                v[j] = (col < 3) ? (__bf16)Wout[(32 * c + 8 * g + j) * 3 + col] : (__bf16)0.0f;
            *(bf16x8*)(F + (((12 + c) * 64 + lane) << 4)) = v;
        }
        f32x4 c3 = {0.f, 0.f, 0.f, 0.f};
        if (g == 0) { c3[0] = bout[0]; c3[1] = bout[1]; c3[2] = bout[2]; }
        *(f32x4*)(F + ((18 * 64 + lane) << 4)) = c3;
    } else if (wv == 1 || wv == 2) {
        // a2 for mt = {0,1} (wv 1) or {2,3} (wv 2)
#pragma unroll
        for (int m = 0; m < 2; ++m) {
            const int mt = (wv - 1) * 2 + m;
            const int p2 = permrow(16 * mt + col);
#pragma unroll
            for (int c = 0; c < 2; ++c) {
                bf16x8 v;
#pragma unroll
                for (int j = 0; j < 8; ++j)
                    v[j] = (__bf16)W2[(32 * c + 8 * g + j) * 64 + p2];
                *(bf16x8*)(F + (((4 + mt * 2 + c) * 64 + lane) << 4)) = v;
            }
        }
    } else {
        // c2init
#pragma unroll
        for (int mt = 0; mt < 4; ++mt) {
            f32x4 v;
#pragma unroll
            for (int r = 0; r < 4; ++r)
                v[r] = b2[permrow(16 * mt + 4 * g + r)];
            *(f32x4*)(F + (((14 + mt) * 64 + lane) << 4)) = v;
        }
    }
}

// ---------------- Kernel 1: 3-layer MLP fully on MFMA, 2 sp-chains/iter ----
// grid (32, 64), block 256 (4 waves). Wave w: 16 points b = (bx*4+w)*16+col.
// Preamble = 19 coalesced dwordx4 loads from the fragment cache (L2-hot).
// Per iteration, TWO independent chains (sp, sp+1) sharing input loads:
//   MFMA1 x4 -> relu_pack -> MFMA2 x8 -> relu_pack -> MFMA3 x2 ; Hermite+store.
// All bf16 conversion via packed v_cvt_pk_bf16_f32 (no element inserts).
__global__ __launch_bounds__(256, 3) void mlp_z_kernel(
    const float* __restrict__ ys,    // (B, S, 2)
    const char* __restrict__ F,      // fragment cache
    float* __restrict__ z)           // (SM1, BATCH)
{
    const int lane = threadIdx.x & 63;
    const int wv   = threadIdx.x >> 6;
    const int col  = lane & 15;

    const int b   = (blockIdx.x * 4 + wv) * 16 + col;
    const int sp0 = blockIdx.y * (2 * PAIRS);
    const int omax = (SFULL - 1) - sp0;  // last valid float2 offset from base2

    // ---- coalesced fragment loads ----
    bf16x8 a1[4], a2[4][2], a3[2];
    f32x4 c2init[4], c3init;
#pragma unroll
    for (int mt = 0; mt < 4; ++mt) {
        a1[mt]       = *(const bf16x8*)(F + ((mt * 64 + lane) << 4));
        a2[mt][0]    = *(const bf16x8*)(F + (((4 + mt * 2) * 64 + lane) << 4));
        a2[mt][1]    = *(const bf16x8*)(F + (((5 + mt * 2) * 64 + lane) << 4));
        c2init[mt]   = *(const f32x4*)(F + (((14 + mt) * 64 + lane) << 4));
    }
    a3[0]  = *(const bf16x8*)(F + ((12 * 64 + lane) << 4));
    a3[1]  = *(const bf16x8*)(F + ((13 * 64 + lane) << 4));
    c3init = *(const f32x4*)(F + ((18 * 64 + lane) << 4));

    const f32x4 zero4 = {0.f, 0.f, 0.f, 0.f};

    const float2* base2 = reinterpret_cast<const float2*>(ys) + ((size_t)b * SFULL + sp0);
    float* zb = z + (size_t)sp0 * BATCH + b;

    float2 qa = base2[0];
    float2 qb = base2[1];
    float2 qc = base2[2];

    for (int it = 0; it < PAIRS; ++it) {
        // prefetch next pair's inputs (offsets clamped -> always in-bounds)
        const int o1n = min(2 * it + 3, omax);
        const int o2n = min(2 * it + 4, omax);
        const float2 nb = base2[o1n];
        const float2 nc = base2[o2n];

        // chain A: sp = sp0+2it ; chain B: sp+1
        const float x0a = qa.y, ta = qb.x, xta = qb.y;
        const float x0b = qb.y, tb = qc.x, xtb = qc.y;

        const bf16x8 f0a = feat_pack(xta, ta, x0a);
        const bf16x8 f0b = feat_pack(xtb, tb, x0b);

        // ---- layer 1 (bias folded in) ----
        f32x4 acc1a[4], acc1b[4];
#pragma unroll
        for (int mt = 0; mt < 4; ++mt) {
            acc1a[mt] = __builtin_amdgcn_mfma_f32_16x16x32_bf16(a1[mt], f0a, zero4, 0, 0, 0);
            acc1b[mt] = __builtin_amdgcn_mfma_f32_16x16x32_bf16(a1[mt], f0b, zero4, 0, 0, 0);
        }

        // relu + packed cvt -> B-frags
        bf16x8 hfa[2], hfb[2];
#pragma unroll
        for (int c = 0; c < 2; ++c) {
            hfa[c] = relu_pack(acc1a[2 * c], acc1a[2 * c + 1]);
            hfb[c] = relu_pack(acc1b[2 * c], acc1b[2 * c + 1]);
        }

        // ---- layer 2 ----
        f32x4 acc2a[4], acc2b[4];
#pragma unroll
        for (int mt = 0; mt < 4; ++mt) {
            acc2a[mt] = __builtin_amdgcn_mfma_f32_16x16x32_bf16(a2[mt][0], hfa[0], c2init[mt], 0, 0, 0);
            acc2b[mt] = __builtin_amdgcn_mfma_f32_16x16x32_bf16(a2[mt][0], hfb[0], c2init[mt], 0, 0, 0);
        }
#pragma unroll
        for (int mt = 0; mt < 4; ++mt) {
            acc2a[mt] = __builtin_amdgcn_mfma_f32_16x16x32_bf16(a2[mt][1], hfa[1], acc2a[mt], 0, 0, 0);
            acc2b[mt] = __builtin_amdgcn_mfma_f32_16x16x32_bf16(a2[mt][1], hfb[1], acc2b[mt], 0, 0, 0);
        }

        bf16x8 h2fa[2], h2fb[2];
#pragma unroll
        for (int c = 0; c < 2; ++c) {
            h2fa[c] = relu_pack(acc2a[2 * c], acc2a[2 * c + 1]);
            h2fb[c] = relu_pack(acc2b[2 * c], acc2b[2 * c + 1]);
        }

        // ---- layer 3 ----
        f32x4 acc3a, acc3b;
        acc3a = __builtin_amdgcn_mfma_f32_16x16x32_bf16(a3[0], h2fa[0], c3init, 0, 0, 0);
        acc3b = __builtin_amdgcn_mfma_f32_16x16x32_bf16(a3[0], h2fb[0], c3init, 0, 0, 0);
        acc3a = __builtin_amdgcn_mfma_f32_16x16x32_bf16(a3[1], h2fa[1], acc3a, 0, 0, 0);
        acc3b = __builtin_amdgcn_mfma_f32_16x16x32_bf16(a3[1], h2fb[1], acc3b, 0, 0, 0);

        // Hermite: z = c0 + c1*(2x) + c2*(4x^2-2)
        const float zva = fmaf(acc3a[2], fmaf(4.0f * xta, xta, -2.0f),
                          fmaf(acc3a[1], xta + xta, acc3a[0]));
        const float zvb = fmaf(acc3b[2], fmaf(4.0f * xtb, xtb, -2.0f),
                          fmaf(acc3b[1], xtb + xtb, acc3b[0]));

        if (lane < 16) {
            zb[(size_t)(2 * it) * BATCH] = zva;
            if (sp0 + 2 * it + 1 < SM1)  // only skips (by=63, it=7) second sp
                zb[(size_t)(2 * it + 1) * BATCH] = zvb;
        }

        qa = qc; qb = nb; qc = nc;
    }
}

// ---------------- reduction helpers ----------------
__device__ __forceinline__ float blk_reduce_max(float v) {
    __shared__ float s[4];
#pragma unroll
    for (int off = 32; off >= 1; off >>= 1) v = fmaxf(v, __shfl_xor(v, off));
    if ((threadIdx.x & 63) == 0) s[threadIdx.x >> 6] = v;
    __syncthreads();
    v = fmaxf(fmaxf(s[0], s[1]), fmaxf(s[2], s[3]));
    __syncthreads();
    return v;
}

__device__ __forceinline__ float blk_reduce_sum(float v) {
    __shared__ float s[4];
#pragma unroll
    for (int off = 32; off >= 1; off >>= 1) v += __shfl_xor(v, off);
    if ((threadIdx.x & 63) == 0) s[threadIdx.x >> 6] = v;
    __syncthreads();
    v = (s[0] + s[1]) + (s[2] + s[3]);
    __syncthreads();
    return v;
}

// ---------------- Kernel 2: per-column softmax + logclip sum ----------------
__global__ __launch_bounds__(256) void col_softmax_kernel(
    const float* __restrict__ z, float* __restrict__ colsum)
{
    const int sp = blockIdx.x;
    const int tid = threadIdx.x;
    const float* col = z + (size_t)sp * BATCH;

    float vals[8];
    float m = -3.4e38f;
#pragma unroll
    for (int i = 0; i < 8; ++i) {
        vals[i] = col[tid + 256 * i];
        m = fmaxf(m, vals[i]);
    }
    const float M = blk_reduce_max(m);

    float se = 0.0f;
#pragma unroll
    for (int i = 0; i < 8; ++i) se += __expf(vals[i] - M);
    const float S = blk_reduce_sum(se);
    const float L = __logf(S);

    float acc = 0.0f;
#pragma unroll
    for (int i = 0; i < 8; ++i) acc += fmaxf(vals[i] - M - L, LN_CLAMP);
    const float T = blk_reduce_sum(acc);
    if (tid == 0) colsum[sp] = T;
}

// ---------------- Kernel 3: final scalar ----------------
__global__ __launch_bounds__(256) void final_reduce_kernel(
    const float* __restrict__ colsum, float* __restrict__ out)
{
    const int tid = threadIdx.x;
    float v = 0.0f;
    for (int i = tid; i < SM1; i += 256) v += colsum[i];
    const float T = blk_reduce_sum(v);
    if (tid == 0) out[0] = T / (float)BATCH;
}

extern "C" void kernel_launch(void* const* d_in, const int* in_sizes, int n_in,
                              void* d_out, int out_size, void* d_ws, size_t ws_size,
                              hipStream_t stream) {
    const float* ys   = (const float*)d_in[0];
    const float* W1   = (const float*)d_in[1];
    const float* b1   = (const float*)d_in[2];
    const float* W2   = (const float*)d_in[3];
    const float* b2   = (const float*)d_in[4];
    const float* Wout = (const float*)d_in[5];
    const float* bout = (const float*)d_in[6];
    float* out = (float*)d_out;

    float* z      = (float*)d_ws;                         // SM1*BATCH floats
    float* colsum = z + (size_t)SM1 * BATCH;              // SM1 floats
    // fragment cache after colsum, 16B aligned
    size_t fo = ((size_t)SM1 * BATCH + SM1) * sizeof(float);
    fo = (fo + 15) & ~(size_t)15;
    char* F = (char*)d_ws + fo;

    frag_setup_kernel<<<1, 256, 0, stream>>>(W1, b1, W2, b2, Wout, bout, F);
    dim3 grid1(32, 64);  // 32*4 waves * 16 pts = 2048 b ; 64*16 = 1024 sp slots
    mlp_z_kernel<<<grid1, 256, 0, stream>>>(ys, F, z);
    col_softmax_kernel<<<SM1, 256, 0, stream>>>(z, colsum);
    final_reduce_kernel<<<1, 256, 0, stream>>>(colsum, out);
}

// Round 8
// 48.688 us; speedup vs baseline: 1.2198x; 1.2198x over previous
//
#include <hip/hip_runtime.h>
#include <hip/hip_bf16.h>

#define HIDDEN 64
#define BATCH 2048
#define SFULL 1024
#define SM1 1023
#define LN_CLAMP -23.025850929940457f  // ln(1e-10)
#define SP_PER 16                      // grid.y = 64 -> 64*16 = 1024 sp slots

typedef __bf16 bf16x8 __attribute__((ext_vector_type(8)));
typedef float  f32x4  __attribute__((ext_vector_type(4)));
typedef float  f32x16 __attribute__((ext_vector_type(16)));

// Fragment cache: 22 units of [64 lanes][16B].
//  u 0,1   : a1[mt]        (bf16x8)   layer-1 A (bias folded at k=3)
//  u 2..9  : a2[mt][c]     (u = 2 + mt*4 + c)
//  u 10..13: a3[c]
//  u 14..21: c2init[mt] regs 4q..4q+3 (u = 14 + mt*4 + q, f32x4)
#define FRAG_UNITS 22

// sigma: D-row (32x32 layout: row=(r&3)+8*(r>>2)+4*hi, tile mt) -> hidden idx
// chosen so the D fragment is per-lane EXACTLY the next mfma's B fragment
// (B k-index = 16c + 8*hi + j with c=r>>2, j=(r&3)+4*mt  ==> k == sigma).
__device__ __forceinline__ int sig(int rg) {
    return 16 * ((rg >> 3) & 3) + 8 * ((rg >> 2) & 1) + (rg & 3) + 4 * (rg >> 5);
}

// ---------------- Kernel 0: one-time fragment gather (1 block) -------------
__global__ __launch_bounds__(256) void frag_setup_kernel(
    const float* __restrict__ W1, const float* __restrict__ b1,
    const float* __restrict__ W2, const float* __restrict__ b2,
    const float* __restrict__ Wout, char* __restrict__ F)
{
    const int l    = threadIdx.x & 63;
    const int wv   = threadIdx.x >> 6;
    const int pcol = l & 31;
    const int hi   = l >> 5;

    if (wv == 0) {
        // a1[mt]: A[row=pcol][k=8hi+j] = W1aug[k][sig(32mt+pcol)]
#pragma unroll
        for (int mt = 0; mt < 2; ++mt) {
            const int hout = sig(32 * mt + pcol);
            bf16x8 v;
#pragma unroll
            for (int j = 0; j < 8; ++j) {
                const int k = 8 * hi + j;
                v[j] = (k < 3) ? (__bf16)W1[k * 64 + hout]
                     : (k == 3) ? (__bf16)b1[hout] : (__bf16)0.0f;
            }
            *(bf16x8*)(F + ((mt * 64 + l) << 4)) = v;
        }
        // a3[c]: A[row=pcol][k=16c+8hi+j] = (pcol<3)? Wout[k][pcol] : 0
#pragma unroll
        for (int c = 0; c < 4; ++c) {
            bf16x8 v;
#pragma unroll
            for (int j = 0; j < 8; ++j) {
                const int k = 16 * c + 8 * hi + j;
                v[j] = (pcol < 3) ? (__bf16)Wout[k * 3 + pcol] : (__bf16)0.0f;
            }
            *(bf16x8*)(F + (((10 + c) * 64 + l) << 4)) = v;
        }
    } else if (wv == 1 || wv == 2) {
        // a2[mt][c]: A[row=pcol][k=16c+8hi+j] = W2[k][sig(32mt+pcol)]
        const int mt = wv - 1;
        const int hout = sig(32 * mt + pcol);
#pragma unroll
        for (int c = 0; c < 4; ++c) {
            bf16x8 v;
#pragma unroll
            for (int j = 0; j < 8; ++j)
                v[j] = (__bf16)W2[(16 * c + 8 * hi + j) * 64 + hout];
            *(bf16x8*)(F + (((2 + mt * 4 + c) * 64 + l) << 4)) = v;
        }
    } else {
        // c2init[mt] reg r: b2[sig(32mt + (r&3)+8*(r>>2)+4*hi)]
#pragma unroll
        for (int mt = 0; mt < 2; ++mt)
#pragma unroll
            for (int q = 0; q < 4; ++q) {
                f32x4 v;
#pragma unroll
                for (int rr = 0; rr < 4; ++rr) {
                    const int r = 4 * q + rr;
                    v[rr] = b2[16 * (r >> 2) + 8 * hi + (r & 3) + 4 * mt];
                }
                *(f32x4*)(F + (((14 + mt * 4 + q) * 64 + l) << 4)) = v;
            }
    }
}

// ---------------- Kernel 1: 3-layer MLP on 32x32x16 MFMA -------------------
// grid (16, 64), block 256 (4 waves). Wave w owns 32 points:
//   b = (blockIdx.x*4 + w)*32 + (lane&31), one sp per iteration.
// Per iteration (single chain, 14 MFMA for 32 points):
//   L1: 2x mfma_32x32x16 (K=16, k<4 used; B garbage at k>=4 is killed by A=0)
//   relu+cvt (in-lane: h1f[c][(r&3)+4mt] = relu(acc1[mt][4c+(r&3)]))
//   L2: 8x mfma ; relu+cvt ; L3: 4x mfma -> rows 0..2 on hi=0 lanes.
__global__ __launch_bounds__(256, 3) void mlp_z_kernel(
    const float* __restrict__ ys,    // (B, S, 2)
    const char* __restrict__ F,      // fragment cache
    const float* __restrict__ bout,  // (3)
    float* __restrict__ z)           // (SM1, BATCH)
{
    const int l    = threadIdx.x & 63;
    const int wv   = threadIdx.x >> 6;
    const int pcol = l & 31;

    const int b   = (blockIdx.x * 4 + wv) * 32 + pcol;
    const int sp0 = blockIdx.y * SP_PER;
    const int omax = (SFULL - 1) - sp0;

    // ---- coalesced fragment loads (L2-hot) ----
    bf16x8 a1[2], a2[2][4], a3[4];
    f32x16 c2init[2];
#pragma unroll
    for (int mt = 0; mt < 2; ++mt) {
        a1[mt] = *(const bf16x8*)(F + ((mt * 64 + l) << 4));
#pragma unroll
        for (int c = 0; c < 4; ++c)
            a2[mt][c] = *(const bf16x8*)(F + (((2 + mt * 4 + c) * 64 + l) << 4));
#pragma unroll
        for (int q = 0; q < 4; ++q) {
            const f32x4 v = *(const f32x4*)(F + (((14 + mt * 4 + q) * 64 + l) << 4));
            c2init[mt][4 * q + 0] = v[0]; c2init[mt][4 * q + 1] = v[1];
            c2init[mt][4 * q + 2] = v[2]; c2init[mt][4 * q + 3] = v[3];
        }
    }
#pragma unroll
    for (int c = 0; c < 4; ++c)
        a3[c] = *(const bf16x8*)(F + (((10 + c) * 64 + l) << 4));

    const float bo0 = bout[0], bo1 = bout[1], bo2 = bout[2];

    f32x16 zero16;
#pragma unroll
    for (int i = 0; i < 16; ++i) zero16[i] = 0.0f;

    const float2* base2 = reinterpret_cast<const float2*>(ys) + ((size_t)b * SFULL + sp0);
    float* zb = z + (size_t)sp0 * BATCH + b;

    float2 q0 = base2[0];
    float2 q1 = base2[min(1, omax)];
    float2 qn = base2[min(2, omax)];

    for (int it = 0; it < SP_PER; ++it) {
        const float2 qn2 = base2[min(it + 3, omax)];  // prefetch

        const float x0 = q0.y, t = q1.x, xt = q1.y;

        // feature B-frag {xt,t,x0,1,...}; elems k>=4 multiply A=0 -> any value
        bf16x8 f0;
        f0[0] = (__bf16)xt; f0[1] = (__bf16)t;
        f0[2] = (__bf16)x0; f0[3] = (__bf16)1.0f;
        f0[4] = f0[0]; f0[5] = f0[1]; f0[6] = f0[2]; f0[7] = f0[3];

        // ---- layer 1 ----
        f32x16 acc1_0 = __builtin_amdgcn_mfma_f32_32x32x16_bf16(a1[0], f0, zero16, 0, 0, 0);
        f32x16 acc1_1 = __builtin_amdgcn_mfma_f32_32x32x16_bf16(a1[1], f0, zero16, 0, 0, 0);

        // relu + cvt -> B-frags of layer 2 (pure in-lane)
        bf16x8 h1f[4];
#pragma unroll
        for (int c = 0; c < 4; ++c)
#pragma unroll
            for (int j = 0; j < 4; ++j) {
                h1f[c][j]     = (__bf16)fmaxf(acc1_0[4 * c + j], 0.0f);
                h1f[c][4 + j] = (__bf16)fmaxf(acc1_1[4 * c + j], 0.0f);
            }

        // ---- layer 2 ----
        f32x16 acc2_0 = c2init[0];
        f32x16 acc2_1 = c2init[1];
#pragma unroll
        for (int c = 0; c < 4; ++c) {
            acc2_0 = __builtin_amdgcn_mfma_f32_32x32x16_bf16(a2[0][c], h1f[c], acc2_0, 0, 0, 0);
            acc2_1 = __builtin_amdgcn_mfma_f32_32x32x16_bf16(a2[1][c], h1f[c], acc2_1, 0, 0, 0);
        }

        bf16x8 h2f[4];
#pragma unroll
        for (int c = 0; c < 4; ++c)
#pragma unroll
            for (int j = 0; j < 4; ++j) {
                h2f[c][j]     = (__bf16)fmaxf(acc2_0[4 * c + j], 0.0f);
                h2f[c][4 + j] = (__bf16)fmaxf(acc2_1[4 * c + j], 0.0f);
            }

        // ---- layer 3 ----
        f32x16 acc3 = zero16;
#pragma unroll
        for (int c = 0; c < 4; ++c)
            acc3 = __builtin_amdgcn_mfma_f32_32x32x16_bf16(a3[c], h2f[c], acc3, 0, 0, 0);

        // epilogue: c_n rows 0..2 live on hi=0 lanes (r=0,1,2)
        const float c0 = acc3[0] + bo0;
        const float c1 = acc3[1] + bo1;
        const float c2 = acc3[2] + bo2;
        const float zv = fmaf(c2, fmaf(4.0f * xt, xt, -2.0f),
                         fmaf(c1, xt + xt, c0));

        if (l < 32 && sp0 + it < SM1)
            zb[(size_t)it * BATCH] = zv;

        q0 = q1; q1 = qn; qn = qn2;
    }
}

// ---------------- reduction helpers ----------------
__device__ __forceinline__ float blk_reduce_max(float v) {
    __shared__ float s[4];
#pragma unroll
    for (int off = 32; off >= 1; off >>= 1) v = fmaxf(v, __shfl_xor(v, off));
    if ((threadIdx.x & 63) == 0) s[threadIdx.x >> 6] = v;
    __syncthreads();
    v = fmaxf(fmaxf(s[0], s[1]), fmaxf(s[2], s[3]));
    __syncthreads();
    return v;
}

__device__ __forceinline__ float blk_reduce_sum(float v) {
    __shared__ float s[4];
#pragma unroll
    for (int off = 32; off >= 1; off >>= 1) v += __shfl_xor(v, off);
    if ((threadIdx.x & 63) == 0) s[threadIdx.x >> 6] = v;
    __syncthreads();
    v = (s[0] + s[1]) + (s[2] + s[3]);
    __syncthreads();
    return v;
}

// ---------------- Kernel 2: per-column softmax + logclip sum ----------------
__global__ __launch_bounds__(256) void col_softmax_kernel(
    const float* __restrict__ z, float* __restrict__ colsum)
{
    const int sp = blockIdx.x;
    const int tid = threadIdx.x;
    const float* col = z + (size_t)sp * BATCH;

    float vals[8];
    float m = -3.4e38f;
#pragma unroll
    for (int i = 0; i < 8; ++i) {
        vals[i] = col[tid + 256 * i];
        m = fmaxf(m, vals[i]);
    }
    const float M = blk_reduce_max(m);

    float se = 0.0f;
#pragma unroll
    for (int i = 0; i < 8; ++i) se += __expf(vals[i] - M);
    const float S = blk_reduce_sum(se);
    const float L = __logf(S);

    float acc = 0.0f;
#pragma unroll
    for (int i = 0; i < 8; ++i) acc += fmaxf(vals[i] - M - L, LN_CLAMP);
    const float T = blk_reduce_sum(acc);
    if (tid == 0) colsum[sp] = T;
}

// ---------------- Kernel 3: final scalar ----------------
__global__ __launch_bounds__(256) void final_reduce_kernel(
    const float* __restrict__ colsum, float* __restrict__ out)
{
    const int tid = threadIdx.x;
    float v = 0.0f;
    for (int i = tid; i < SM1; i += 256) v += colsum[i];
    const float T = blk_reduce_sum(v);
    if (tid == 0) out[0] = T / (float)BATCH;
}

extern "C" void kernel_launch(void* const* d_in, const int* in_sizes, int n_in,
                              void* d_out, int out_size, void* d_ws, size_t ws_size,
                              hipStream_t stream) {
    const float* ys   = (const float*)d_in[0];
    const float* W1   = (const float*)d_in[1];
    const float* b1   = (const float*)d_in[2];
    const float* W2   = (const float*)d_in[3];
    const float* b2   = (const float*)d_in[4];
    const float* Wout = (const float*)d_in[5];
    const float* bout = (const float*)d_in[6];
    float* out = (float*)d_out;

    float* z      = (float*)d_ws;                         // SM1*BATCH floats
    float* colsum = z + (size_t)SM1 * BATCH;              // SM1 floats
    size_t fo = ((size_t)SM1 * BATCH + SM1) * sizeof(float);
    fo = (fo + 15) & ~(size_t)15;
    char* F = (char*)d_ws + fo;                           // 22*64*16 = 22.5 KB

    frag_setup_kernel<<<1, 256, 0, stream>>>(W1, b1, W2, b2, Wout, F);
    dim3 grid1(16, 64);  // 16*4 waves * 32 pts = 2048 b ; 64*16 = 1024 sp slots
    mlp_z_kernel<<<grid1, 256, 0, stream>>>(ys, F, bout, z);
    col_softmax_kernel<<<SM1, 256, 0, stream>>>(z, colsum);
    final_reduce_kernel<<<1, 256, 0, stream>>>(colsum, out);
}

// Round 9
// 47.963 us; speedup vs baseline: 1.2383x; 1.0151x over previous
//
#include <hip/hip_runtime.h>
#include <hip/hip_bf16.h>

#define HIDDEN 64
#define BATCH 2048
#define SFULL 1024
#define SM1 1023
#define LN_CLAMP -23.025850929940457f  // ln(1e-10)
#define SP_PER 8                       // grid.y = 128 -> 128*8 = 1024 sp slots

typedef __bf16 bf16x8 __attribute__((ext_vector_type(8)));
typedef float  f32x4  __attribute__((ext_vector_type(4)));
typedef float  f32x16 __attribute__((ext_vector_type(16)));

// Fragment cache: 22 units of [64 lanes][16B].
//  u 0,1   : a1[mt]        (bf16x8)   layer-1 A (bias folded at k=3)
//  u 2..9  : a2[mt][c]     (u = 2 + mt*4 + c)
//  u 10..13: a3[c]
//  u 14..21: c2init[mt] regs 4q..4q+3 (u = 14 + mt*4 + q, f32x4)
#define FRAG_UNITS 22

// sigma: D-row (32x32 layout: row=(r&3)+8*(r>>2)+4*hi, tile mt) -> hidden idx
// chosen so the D fragment is per-lane EXACTLY the next mfma's B fragment
// (B k-index = 16c + 8*hi + j with c=r>>2, j=(r&3)+4*mt  ==> k == sigma).
// Hardware-verified in R7 (absmax 0.0).
__device__ __forceinline__ int sig(int rg) {
    return 16 * ((rg >> 3) & 3) + 8 * ((rg >> 2) & 1) + (rg & 3) + 4 * (rg >> 5);
}

// ---------------- Kernel 0: one-time fragment gather (1 block) -------------
__global__ __launch_bounds__(256) void frag_setup_kernel(
    const float* __restrict__ W1, const float* __restrict__ b1,
    const float* __restrict__ W2, const float* __restrict__ b2,
    const float* __restrict__ Wout, char* __restrict__ F)
{
    const int l    = threadIdx.x & 63;
    const int wv   = threadIdx.x >> 6;
    const int pcol = l & 31;
    const int hi   = l >> 5;

    if (wv == 0) {
        // a1[mt]: A[row=pcol][k=8hi+j] = W1aug[k][sig(32mt+pcol)]
#pragma unroll
        for (int mt = 0; mt < 2; ++mt) {
            const int hout = sig(32 * mt + pcol);
            bf16x8 v;
#pragma unroll
            for (int j = 0; j < 8; ++j) {
                const int k = 8 * hi + j;
                v[j] = (k < 3) ? (__bf16)W1[k * 64 + hout]
                     : (k == 3) ? (__bf16)b1[hout] : (__bf16)0.0f;
            }
            *(bf16x8*)(F + ((mt * 64 + l) << 4)) = v;
        }
        // a3[c]: A[row=pcol][k=16c+8hi+j] = (pcol<3)? Wout[k][pcol] : 0
#pragma unroll
        for (int c = 0; c < 4; ++c) {
            bf16x8 v;
#pragma unroll
            for (int j = 0; j < 8; ++j) {
                const int k = 16 * c + 8 * hi + j;
                v[j] = (pcol < 3) ? (__bf16)Wout[k * 3 + pcol] : (__bf16)0.0f;
            }
            *(bf16x8*)(F + (((10 + c) * 64 + l) << 4)) = v;
        }
    } else if (wv == 1 || wv == 2) {
        // a2[mt][c]: A[row=pcol][k=16c+8hi+j] = W2[k][sig(32mt+pcol)]
        const int mt = wv - 1;
        const int hout = sig(32 * mt + pcol);
#pragma unroll
        for (int c = 0; c < 4; ++c) {
            bf16x8 v;
#pragma unroll
            for (int j = 0; j < 8; ++j)
                v[j] = (__bf16)W2[(16 * c + 8 * hi + j) * 64 + hout];
            *(bf16x8*)(F + (((2 + mt * 4 + c) * 64 + l) << 4)) = v;
        }
    } else {
        // c2init[mt] reg r: b2[sig-row r of tile mt] = b2[16*(r>>2)+8*hi+(r&3)+4*mt]
#pragma unroll
        for (int mt = 0; mt < 2; ++mt)
#pragma unroll
            for (int q = 0; q < 4; ++q) {
                f32x4 v;
#pragma unroll
                for (int rr = 0; rr < 4; ++rr) {
                    const int r = 4 * q + rr;
                    v[rr] = b2[16 * (r >> 2) + 8 * hi + (r & 3) + 4 * mt];
                }
                *(f32x4*)(F + (((14 + mt * 4 + q) * 64 + l) << 4)) = v;
            }
    }
}

// ---------------- Kernel 1: 3-layer MLP on 32x32x16 MFMA -------------------
// grid (16, 128), block 256 (4 waves). Wave w owns 32 points:
//   b = (blockIdx.x*4 + w)*32 + (lane&31), one sp per iteration, 8 iters.
// Per iteration (14 MFMA for 32 points):
//   L1: 2x mfma (K=16, k<4 used) -> relu+cvt (in-lane)
//   L2: 2 parallel chains of 4    -> relu+cvt
//   L3: 2 parallel chains of 2, rows 0..2 combined with 3 scalar adds.
// #pragma unroll 2 interleaves two independent sp-chains for ILP.
__global__ __launch_bounds__(256, 3) void mlp_z_kernel(
    const float* __restrict__ ys,    // (B, S, 2)
    const char* __restrict__ F,      // fragment cache
    const float* __restrict__ bout,  // (3)
    float* __restrict__ z)           // (SM1, BATCH)
{
    const int l    = threadIdx.x & 63;
    const int wv   = threadIdx.x >> 6;
    const int pcol = l & 31;

    const int b   = (blockIdx.x * 4 + wv) * 32 + pcol;
    const int sp0 = blockIdx.y * SP_PER;
    const int omax = (SFULL - 1) - sp0;

    // ---- coalesced fragment loads (L2-hot) ----
    bf16x8 a1[2], a2[2][4], a3[4];
    f32x16 c2init[2];
#pragma unroll
    for (int mt = 0; mt < 2; ++mt) {
        a1[mt] = *(const bf16x8*)(F + ((mt * 64 + l) << 4));
#pragma unroll
        for (int c = 0; c < 4; ++c)
            a2[mt][c] = *(const bf16x8*)(F + (((2 + mt * 4 + c) * 64 + l) << 4));
#pragma unroll
        for (int q = 0; q < 4; ++q) {
            const f32x4 v = *(const f32x4*)(F + (((14 + mt * 4 + q) * 64 + l) << 4));
            c2init[mt][4 * q + 0] = v[0]; c2init[mt][4 * q + 1] = v[1];
            c2init[mt][4 * q + 2] = v[2]; c2init[mt][4 * q + 3] = v[3];
        }
    }
#pragma unroll
    for (int c = 0; c < 4; ++c)
        a3[c] = *(const bf16x8*)(F + (((10 + c) * 64 + l) << 4));

    const float bo0 = bout[0], bo1 = bout[1], bo2 = bout[2];

    f32x16 zero16;
#pragma unroll
    for (int i = 0; i < 16; ++i) zero16[i] = 0.0f;

    const float2* base2 = reinterpret_cast<const float2*>(ys) + ((size_t)b * SFULL + sp0);
    float* zb = z + (size_t)sp0 * BATCH + b;

    float2 q0 = base2[0];
    float2 q1 = base2[min(1, omax)];
    float2 qn = base2[min(2, omax)];

#pragma unroll 2
    for (int it = 0; it < SP_PER; ++it) {
        const float2 qn2 = base2[min(it + 3, omax)];  // prefetch

        const float x0 = q0.y, t = q1.x, xt = q1.y;

        // feature B-frag {xt,t,x0,1,...}; elems k>=4 multiply A=0 -> any value
        bf16x8 f0;
        f0[0] = (__bf16)xt; f0[1] = (__bf16)t;
        f0[2] = (__bf16)x0; f0[3] = (__bf16)1.0f;
        f0[4] = f0[0]; f0[5] = f0[1]; f0[6] = f0[2]; f0[7] = f0[3];

        // ---- layer 1 ----
        f32x16 acc1_0 = __builtin_amdgcn_mfma_f32_32x32x16_bf16(a1[0], f0, zero16, 0, 0, 0);
        f32x16 acc1_1 = __builtin_amdgcn_mfma_f32_32x32x16_bf16(a1[1], f0, zero16, 0, 0, 0);

        // relu + cvt -> B-frags of layer 2 (pure in-lane)
        bf16x8 h1f[4];
#pragma unroll
        for (int c = 0; c < 4; ++c)
#pragma unroll
            for (int j = 0; j < 4; ++j) {
                h1f[c][j]     = (__bf16)fmaxf(acc1_0[4 * c + j], 0.0f);
                h1f[c][4 + j] = (__bf16)fmaxf(acc1_1[4 * c + j], 0.0f);
            }

        // ---- layer 2 (two parallel 4-chains) ----
        f32x16 acc2_0 = c2init[0];
        f32x16 acc2_1 = c2init[1];
#pragma unroll
        for (int c = 0; c < 4; ++c) {
            acc2_0 = __builtin_amdgcn_mfma_f32_32x32x16_bf16(a2[0][c], h1f[c], acc2_0, 0, 0, 0);
            acc2_1 = __builtin_amdgcn_mfma_f32_32x32x16_bf16(a2[1][c], h1f[c], acc2_1, 0, 0, 0);
        }

        bf16x8 h2f[4];
#pragma unroll
        for (int c = 0; c < 4; ++c)
#pragma unroll
            for (int j = 0; j < 4; ++j) {
                h2f[c][j]     = (__bf16)fmaxf(acc2_0[4 * c + j], 0.0f);
                h2f[c][4 + j] = (__bf16)fmaxf(acc2_1[4 * c + j], 0.0f);
            }

        // ---- layer 3 (two parallel 2-chains; only rows 0..2 consumed) ----
        f32x16 acc3a, acc3b;
        acc3a = __builtin_amdgcn_mfma_f32_32x32x16_bf16(a3[0], h2f[0], zero16, 0, 0, 0);
        acc3b = __builtin_amdgcn_mfma_f32_32x32x16_bf16(a3[2], h2f[2], zero16, 0, 0, 0);
        acc3a = __builtin_amdgcn_mfma_f32_32x32x16_bf16(a3[1], h2f[1], acc3a, 0, 0, 0);
        acc3b = __builtin_amdgcn_mfma_f32_32x32x16_bf16(a3[3], h2f[3], acc3b, 0, 0, 0);

        // epilogue: c_n rows 0..2 live on hi=0 lanes (regs 0..2)
        const float c0 = acc3a[0] + acc3b[0] + bo0;
        const float c1 = acc3a[1] + acc3b[1] + bo1;
        const float c2 = acc3a[2] + acc3b[2] + bo2;
        const float zv = fmaf(c2, fmaf(4.0f * xt, xt, -2.0f),
                         fmaf(c1, xt + xt, c0));

        if (l < 32 && sp0 + it < SM1)
            zb[(size_t)it * BATCH] = zv;

        q0 = q1; q1 = qn; qn = qn2;
    }
}

// ---------------- reduction helpers ----------------
__device__ __forceinline__ float blk_reduce_max(float v) {
    __shared__ float s[4];
#pragma unroll
    for (int off = 32; off >= 1; off >>= 1) v = fmaxf(v, __shfl_xor(v, off));
    if ((threadIdx.x & 63) == 0) s[threadIdx.x >> 6] = v;
    __syncthreads();
    v = fmaxf(fmaxf(s[0], s[1]), fmaxf(s[2], s[3]));
    __syncthreads();
    return v;
}

__device__ __forceinline__ float blk_reduce_sum(float v) {
    __shared__ float s[4];
#pragma unroll
    for (int off = 32; off >= 1; off >>= 1) v += __shfl_xor(v, off);
    if ((threadIdx.x & 63) == 0) s[threadIdx.x >> 6] = v;
    __syncthreads();
    v = (s[0] + s[1]) + (s[2] + s[3]);
    __syncthreads();
    return v;
}

// ---------------- Kernel 2: per-column softmax + logclip sum ----------------
__global__ __launch_bounds__(256) void col_softmax_kernel(
    const float* __restrict__ z, float* __restrict__ colsum)
{
    const int sp = blockIdx.x;
    const int tid = threadIdx.x;
    const float* col = z + (size_t)sp * BATCH;

    float vals[8];
    float m = -3.4e38f;
#pragma unroll
    for (int i = 0; i < 8; ++i) {
        vals[i] = col[tid + 256 * i];
        m = fmaxf(m, vals[i]);
    }
    const float M = blk_reduce_max(m);

    float se = 0.0f;
#pragma unroll
    for (int i = 0; i < 8; ++i) se += __expf(vals[i] - M);
    const float S = blk_reduce_sum(se);
    const float L = __logf(S);

    float acc = 0.0f;
#pragma unroll
    for (int i = 0; i < 8; ++i) acc += fmaxf(vals[i] - M - L, LN_CLAMP);
    const float T = blk_reduce_sum(acc);
    if (tid == 0) colsum[sp] = T;
}

// ---------------- Kernel 3: final scalar ----------------
__global__ __launch_bounds__(256) void final_reduce_kernel(
    const float* __restrict__ colsum, float* __restrict__ out)
{
    const int tid = threadIdx.x;
    float v = 0.0f;
    for (int i = tid; i < SM1; i += 256) v += colsum[i];
    const float T = blk_reduce_sum(v);
    if (tid == 0) out[0] = T / (float)BATCH;
}

extern "C" void kernel_launch(void* const* d_in, const int* in_sizes, int n_in,
                              void* d_out, int out_size, void* d_ws, size_t ws_size,
                              hipStream_t stream) {
    const float* ys   = (const float*)d_in[0];
    const float* W1   = (const float*)d_in[1];
    const float* b1   = (const float*)d_in[2];
    const float* W2   = (const float*)d_in[3];
    const float* b2   = (const float*)d_in[4];
    const float* Wout = (const float*)d_in[5];
    const float* bout = (const float*)d_in[6];
    float* out = (float*)d_out;

    float* z      = (float*)d_ws;                         // SM1*BATCH floats
    float* colsum = z + (size_t)SM1 * BATCH;              // SM1 floats
    size_t fo = ((size_t)SM1 * BATCH + SM1) * sizeof(float);
    fo = (fo + 15) & ~(size_t)15;
    char* F = (char*)d_ws + fo;                           // 22*64*16 = 22.5 KB

    frag_setup_kernel<<<1, 256, 0, stream>>>(W1, b1, W2, b2, Wout, F);
    dim3 grid1(16, 128);  // 16*4 waves * 32 pts = 2048 b ; 128*8 = 1024 sp slots
    mlp_z_kernel<<<grid1, 256, 0, stream>>>(ys, F, bout, z);
    col_softmax_kernel<<<SM1, 256, 0, stream>>>(z, colsum);
    final_reduce_kernel<<<1, 256, 0, stream>>>(colsum, out);
}